// Round 3
// baseline (604.935 us; speedup 1.0000x reference)
//
#include <hip/hip_runtime.h>

// Problem: b=2, s=2048, DIM=HIDDEN=1024, heads=16.
// SCALE = 1024^-5 = 2^-50 => all scores ~1e-14 => softmax is uniform over the
// mask-enabled positions to within ~1e-13 relative. Hence:
//   attn[h,b,i,j] = mask[b,j] / cnt[b]
//   out[b,i,:]    = ((sum_j mask*x[b,j,:]) / cnt[b]) @ Wv^T @ Wo^T   (i-independent)
// Kernel is therefore streaming-store bound: 554 MB writes + ~42 MB reads.
// Measured floor: harness re-poison of d_ws/d_out (~455 us of fillBuffer inside
// the timed window) + ~105 us of our traffic at ~6.25 TB/s.

#define DIMN 1024
#define SEQ  2048
#define BATCH 2

// native vector type for __builtin_nontemporal_store (HIP float4 is a struct)
typedef float vfloat4 __attribute__((ext_vector_type(4)));

// ws float offsets
#define WS_XSUM  0      // [b][d] masked column sums, 2048
#define WS_CNT   2048   // cnt[b], 2
#define WS_TMP   2052   // [b][h] = xbar @ Wv^T, 2048
#define WS_OVEC  4100   // [b][d] = tmp @ Wo^T, 2048

// grid (128, 2) x 256: block = (16-row chunk, batch). Wide enough to use 256 CUs.
__global__ void k_reduce_x(const float* __restrict__ x,
                           const int* __restrict__ mask,
                           float* __restrict__ ws) {
    const int b = blockIdx.y;
    const int tid = threadIdx.x;
    const int j0 = blockIdx.x * 16;
    const float* xb = x + (size_t)b * SEQ * DIMN;

    float a0 = 0.f, a1 = 0.f, a2 = 0.f, a3 = 0.f;
    for (int j = j0; j < j0 + 16; ++j) {
        if (mask[b * SEQ + j]) {            // wave-uniform branch
            const float* row = xb + (size_t)j * DIMN;
            a0 += row[tid];
            a1 += row[tid + 256];
            a2 += row[tid + 512];
            a3 += row[tid + 768];
        }
    }
    atomicAdd(&ws[WS_XSUM + b * DIMN + tid],       a0);
    atomicAdd(&ws[WS_XSUM + b * DIMN + tid + 256], a1);
    atomicAdd(&ws[WS_XSUM + b * DIMN + tid + 512], a2);
    atomicAdd(&ws[WS_XSUM + b * DIMN + tid + 768], a3);

    // mask count for this 16-row chunk (lanes 0..15 of wave 0)
    if (tid < 16) {
        float s = (mask[b * SEQ + j0 + tid] != 0) ? 1.f : 0.f;
        s += __shfl_down(s, 8, 64);
        s += __shfl_down(s, 4, 64);
        s += __shfl_down(s, 2, 64);
        s += __shfl_down(s, 1, 64);
        if (tid == 0) atomicAdd(&ws[WS_CNT + b], s);
    }
}

// One 64-lane wave per row: vout[b][r] = dot(W[r,:], vin[b,:]) (/cnt[b] if divide)
__global__ void k_matvec(const float* __restrict__ W,
                         const float* __restrict__ vin,
                         float* __restrict__ vout,
                         const float* __restrict__ cnt,
                         int divide) {
    const int gw = (blockIdx.x * 256 + threadIdx.x) >> 6;  // 0..2047
    const int lane = threadIdx.x & 63;
    const int b = gw >> 10;
    const int r = gw & 1023;
    const float* wr = W + (size_t)r * DIMN;
    const float* vb = vin + b * DIMN;
    float s = 0.f;
#pragma unroll
    for (int k = 0; k < DIMN / 64; ++k)
        s += wr[lane + k * 64] * vb[lane + k * 64];
#pragma unroll
    for (int off = 32; off; off >>= 1) s += __shfl_down(s, off, 64);
    if (lane == 0) {
        if (divide) s /= cnt[b];
        vout[b * DIMN + r] = s;
    }
}

// Fused epilogue: blocks [0,256) fill out (2^20 float4), blocks [256,8448) fill
// attn (2^25 float4). Attn values computed inline from mask (16 KB, L1-hot).
__global__ void k_megafill(float* __restrict__ out, float* __restrict__ attn,
                           const int* __restrict__ mask,
                           const float* __restrict__ ws) {
    const int tid = threadIdx.x;
    if (blockIdx.x < 256) {
        const float* ovec = ws + WS_OVEC;
#pragma unroll 4
        for (int f = blockIdx.x * 256 + tid; f < (1 << 20); f += 256 * 256) {
            const int b  = f >> 19;
            const int d4 = f & 255;
            vfloat4 v = ((const vfloat4*)(ovec + b * DIMN))[d4];
            __builtin_nontemporal_store(v, ((vfloat4*)out) + f);
        }
    } else {
        const float r0 = 1.0f / ws[WS_CNT];
        const float r1 = 1.0f / ws[WS_CNT + 1];
        const int4* m4 = (const int4*)mask;
        const int stride = 8192 * 256;
#pragma unroll 4
        for (int f = (blockIdx.x - 256) * 256 + tid; f < (1 << 25); f += stride) {
            const int j4 = f & 511;            // j = 4*j4
            const int b  = (f >> 20) & 1;      // attn flat = ((h*2+b)*2048+i)*512 + j4
            const int4 m = m4[b * 512 + j4];
            const float r = b ? r1 : r0;
            vfloat4 v;
            v.x = m.x ? r : 0.f;
            v.y = m.y ? r : 0.f;
            v.z = m.z ? r : 0.f;
            v.w = m.w ? r : 0.f;
            __builtin_nontemporal_store(v, ((vfloat4*)attn) + f);
        }
    }
}

extern "C" void kernel_launch(void* const* d_in, const int* in_sizes, int n_in,
                              void* d_out, int out_size, void* d_ws, size_t ws_size,
                              hipStream_t stream) {
    const float* x    = (const float*)d_in[0];
    const int*   mask = (const int*)d_in[1];
    // d_in[2]=Wq, d_in[3]=Wk: provably irrelevant at SCALE = 2^-50
    const float* Wv   = (const float*)d_in[4];
    const float* Wo   = (const float*)d_in[5];

    float* ws   = (float*)d_ws;
    float* out  = (float*)d_out;                        // 2*2048*1024
    float* attn = out + (size_t)BATCH * SEQ * DIMN;     // 16*2*2048*2048

    // zero the atomic accumulation region (xsum + cnt)
    (void)hipMemsetAsync(d_ws, 0, (WS_CNT + 2) * sizeof(float), stream);

    dim3 rg(128, BATCH);
    k_reduce_x<<<rg, 256, 0, stream>>>(x, mask, ws);
    k_matvec<<<512, 256, 0, stream>>>(Wv, ws + WS_XSUM, ws + WS_TMP,  ws + WS_CNT, 1);
    k_matvec<<<512, 256, 0, stream>>>(Wo, ws + WS_TMP,  ws + WS_OVEC, ws + WS_CNT, 0);
    k_megafill<<<8448, 256, 0, stream>>>(out, attn, mask, ws);
}